// Round 1
// baseline (47.283 us; speedup 1.0000x reference)
//
#include <hip/hip_runtime.h>
#include <math.h>

#define B_  8
#define L_  4096
#define C_  256
#define TL  64

__global__ __launch_bounds__(256, 2)
void dconv1d_kernel(const float* __restrict__ x,
                    const float* __restrict__ w_off,
                    const float* __restrict__ b_off,
                    const float* __restrict__ w_mask,
                    const float* __restrict__ b_mask,
                    float* __restrict__ out) {
    __shared__ float s_tile[TL * C_];   // 64 KB, XOR-swizzled columns
    __shared__ int   s_fl[3][TL];
    __shared__ int   s_ce[3][TL];
    __shared__ float s_al[3][TL];
    __shared__ float s_mk[3][TL];

    const int tid  = threadIdx.x;
    const int lane = tid & 63;
    const int g    = tid >> 6;          // wave id 0..3
    const int l0   = blockIdx.x * TL;
    const int b    = blockIdx.y;
    const float* __restrict__ xb = x + (size_t)b * L_ * C_;

    // ---- weights into registers: w_r[o][j*3+t] for c = lane*4+j ----
    float w_r[6][12];
    #pragma unroll
    for (int o = 0; o < 6; ++o) {
        const float* ws = (o < 3) ? (w_off + o * (C_ * 3))
                                  : (w_mask + (o - 3) * (C_ * 3));
        const float4* wp = reinterpret_cast<const float4*>(ws + lane * 12);
        float4 q0 = wp[0], q1 = wp[1], q2 = wp[2];
        w_r[o][0]=q0.x; w_r[o][1] =q0.y; w_r[o][2] =q0.z; w_r[o][3] =q0.w;
        w_r[o][4]=q1.x; w_r[o][5] =q1.y; w_r[o][6] =q1.z; w_r[o][7] =q1.w;
        w_r[o][8]=q2.x; w_r[o][9] =q2.y; w_r[o][10]=q2.z; w_r[o][11]=q2.w;
    }

    // ---- phase 1: conv -> per-l params (wave g: ll = g*16 .. g*16+15) ----
    for (int i = 0; i < 16; ++i) {
        const int ll = g * 16 + i;
        const int l  = l0 + ll;
        float acc[6] = {0.f, 0.f, 0.f, 0.f, 0.f, 0.f};
        #pragma unroll
        for (int t = 0; t < 3; ++t) {
            const int row = l - 1 + t;
            if (row >= 0 && row < L_) {
                const float4 xv =
                    *reinterpret_cast<const float4*>(xb + (size_t)row * C_ + lane * 4);
                #pragma unroll
                for (int o = 0; o < 6; ++o) {
                    acc[o] += xv.x * w_r[o][0 + t] + xv.y * w_r[o][3 + t]
                            + xv.z * w_r[o][6 + t] + xv.w * w_r[o][9 + t];
                }
            }
        }
        #pragma unroll
        for (int o = 0; o < 6; ++o) {
            #pragma unroll
            for (int s = 32; s > 0; s >>= 1)
                acc[o] += __shfl_xor(acc[o], s, 64);
        }
        if (lane == 0) {
            #pragma unroll
            for (int k = 0; k < 3; ++k) {
                float off = acc[k] + b_off[k];
                float pos = fminf(fmaxf((float)l + off, 0.0f), (float)(L_ - 1));
                float flf = floorf(pos);
                int   fl  = (int)flf;
                int   ce  = min(fl + 1, L_ - 1);
                s_fl[k][ll] = fl;
                s_ce[k][ll] = ce;
                s_al[k][ll] = pos - flf;
                float z = acc[k + 3] + b_mask[k];
                s_mk[k][ll] = 1.0f / (1.0f + __expf(-z));
            }
        }
    }
    __syncthreads();

    // ---- phase 2: gather + lerp + mask; wave g owns c = g*64 + lane ----
    {
        const int c = tid;  // (g*64 + lane)
        #pragma unroll 4
        for (int ll = 0; ll < TL; ++ll) {
            float v = 0.f;
            #pragma unroll
            for (int k = 0; k < 3; ++k) {
                const int   fl = s_fl[k][ll];
                const int   ce = s_ce[k][ll];
                const float a  = s_al[k][ll];
                const float m  = s_mk[k][ll];
                const float xf = xb[fl * C_ + c];
                const float xc = xb[ce * C_ + c];
                v += (xf + a * (xc - xf)) * m;
            }
            s_tile[ll * C_ + (c ^ (ll & 31))] = v;
        }
    }
    __syncthreads();

    // ---- phase 3: transpose write-out; lane = l index, loop over c ----
    {
        const int lw = lane;  // l_local
        for (int cc = 0; cc < 64; ++cc) {
            const int c = g * 64 + cc;
            const float v = s_tile[lw * C_ + (c ^ (lw & 31))];
            out[((size_t)b * C_ + c) * L_ + l0 + lw] = v;
        }
    }
}

extern "C" void kernel_launch(void* const* d_in, const int* in_sizes, int n_in,
                              void* d_out, int out_size, void* d_ws, size_t ws_size,
                              hipStream_t stream) {
    const float* x      = (const float*)d_in[0];
    const float* w_off  = (const float*)d_in[1];
    const float* b_off  = (const float*)d_in[2];
    const float* w_mask = (const float*)d_in[3];
    const float* b_mask = (const float*)d_in[4];
    float* out = (float*)d_out;

    dim3 grid(L_ / TL, B_);
    dconv1d_kernel<<<grid, 256, 0, stream>>>(x, w_off, b_off, w_mask, b_mask, out);
}

// Round 2
// 38.504 us; speedup vs baseline: 1.2280x; 1.2280x over previous
//
#include <hip/hip_runtime.h>
#include <math.h>

#define B_  8
#define L_  4096
#define C_  256
#define TL  32

__global__ __launch_bounds__(256, 4)
void dconv1d_kernel(const float* __restrict__ x,
                    const float* __restrict__ w_off,
                    const float* __restrict__ b_off,
                    const float* __restrict__ w_mask,
                    const float* __restrict__ b_mask,
                    float* __restrict__ out) {
    __shared__ float s_tile[TL * C_];   // 32 KB, XOR-swizzled columns
    __shared__ int   s_fl[3][TL];
    __shared__ int   s_ce[3][TL];
    __shared__ float s_al[3][TL];
    __shared__ float s_mk[3][TL];

    const int tid  = threadIdx.x;
    const int lane = tid & 63;
    const int g    = tid >> 6;          // wave id 0..3
    const int l0   = blockIdx.x * TL;
    const int b    = blockIdx.y;
    const float* __restrict__ xb = x + (size_t)b * L_ * C_;

    // ---- weights into registers: w_r[o][j*3+t] for c = lane*4+j ----
    float w_r[6][12];
    #pragma unroll
    for (int o = 0; o < 6; ++o) {
        const float* ws = (o < 3) ? (w_off + o * (C_ * 3))
                                  : (w_mask + (o - 3) * (C_ * 3));
        const float4* wp = reinterpret_cast<const float4*>(ws + lane * 12);
        float4 q0 = wp[0], q1 = wp[1], q2 = wp[2];
        w_r[o][0]=q0.x; w_r[o][1] =q0.y; w_r[o][2] =q0.z; w_r[o][3] =q0.w;
        w_r[o][4]=q1.x; w_r[o][5] =q1.y; w_r[o][6] =q1.z; w_r[o][7] =q1.w;
        w_r[o][8]=q2.x; w_r[o][9] =q2.y; w_r[o][10]=q2.z; w_r[o][11]=q2.w;
    }

    // ---- phase 1: conv -> per-l params (wave g: ll = g*8 .. g*8+7) ----
    for (int i = 0; i < TL / 4; ++i) {
        const int ll = g * (TL / 4) + i;
        const int l  = l0 + ll;
        float acc[6] = {0.f, 0.f, 0.f, 0.f, 0.f, 0.f};
        #pragma unroll
        for (int t = 0; t < 3; ++t) {
            const int row = l - 1 + t;
            if (row >= 0 && row < L_) {
                const float4 xv =
                    *reinterpret_cast<const float4*>(xb + (size_t)row * C_ + lane * 4);
                #pragma unroll
                for (int o = 0; o < 6; ++o) {
                    acc[o] += xv.x * w_r[o][0 + t] + xv.y * w_r[o][3 + t]
                            + xv.z * w_r[o][6 + t] + xv.w * w_r[o][9 + t];
                }
            }
        }
        #pragma unroll
        for (int o = 0; o < 6; ++o) {
            #pragma unroll
            for (int s = 32; s > 0; s >>= 1)
                acc[o] += __shfl_xor(acc[o], s, 64);
        }
        if (lane == 0) {
            #pragma unroll
            for (int k = 0; k < 3; ++k) {
                float off = acc[k] + b_off[k];
                float pos = fminf(fmaxf((float)l + off, 0.0f), (float)(L_ - 1));
                float flf = floorf(pos);
                int   fl  = (int)flf;
                int   ce  = min(fl + 1, L_ - 1);
                s_fl[k][ll] = fl;
                s_ce[k][ll] = ce;
                s_al[k][ll] = pos - flf;
                float z = acc[k + 3] + b_mask[k];
                s_mk[k][ll] = 1.0f / (1.0f + __expf(-z));
            }
        }
    }
    __syncthreads();

    // ---- phase 2: gather + lerp + mask; thread owns channel c = tid ----
    {
        const int c = tid;
        #pragma unroll 4
        for (int ll = 0; ll < TL; ++ll) {
            float v = 0.f;
            #pragma unroll
            for (int k = 0; k < 3; ++k) {
                const int   fl = s_fl[k][ll];
                const int   ce = s_ce[k][ll];
                const float a  = s_al[k][ll];
                const float m  = s_mk[k][ll];
                const float xf = xb[fl * C_ + c];
                const float xc = xb[ce * C_ + c];
                v += (xf + a * (xc - xf)) * m;
            }
            s_tile[ll * C_ + (c ^ (ll & 31))] = v;
        }
    }
    __syncthreads();

    // ---- phase 3: transpose write-out ----
    // lw = l index (0..31), 8 c-groups of 32 channels each
    {
        const int lw = tid & 31;
        const int cg = tid >> 5;        // 0..7
        #pragma unroll 8
        for (int cc = 0; cc < 32; ++cc) {
            const int c = cg * 32 + cc;
            const float v = s_tile[lw * C_ + (c ^ lw)];
            out[((size_t)b * C_ + c) * L_ + l0 + lw] = v;
        }
    }
}

extern "C" void kernel_launch(void* const* d_in, const int* in_sizes, int n_in,
                              void* d_out, int out_size, void* d_ws, size_t ws_size,
                              hipStream_t stream) {
    const float* x      = (const float*)d_in[0];
    const float* w_off  = (const float*)d_in[1];
    const float* b_off  = (const float*)d_in[2];
    const float* w_mask = (const float*)d_in[3];
    const float* b_mask = (const float*)d_in[4];
    float* out = (float*)d_out;

    dim3 grid(L_ / TL, B_);
    dconv1d_kernel<<<grid, 256, 0, stream>>>(x, w_off, b_off, w_mask, b_mask, out);
}